// Round 3
// baseline (796.509 us; speedup 1.0000x reference)
//
#include <hip/hip_runtime.h>
#include <hip/hip_bf16.h>
#include <cstdint>

typedef short short8 __attribute__((ext_vector_type(8)));
typedef float floatx4 __attribute__((ext_vector_type(4)));
typedef float f32x4 __attribute__((ext_vector_type(4)));
typedef unsigned short u16;
typedef unsigned short u16x4 __attribute__((ext_vector_type(4)));

#define BB 8192
#define DD 2048
#define HH 4096

static __device__ __forceinline__ u16 f2bf(float x) {
  __hip_bfloat16 h = __float2bfloat16(x);
  return __builtin_bit_cast(u16, h);
}

static __device__ __forceinline__ void glds16(const u16* g, u16* l) {
  __builtin_amdgcn_global_load_lds(
      (const __attribute__((address_space(1))) void*)g,
      (__attribute__((address_space(3))) void*)l, 16, 0, 0);
}

// ---------------- elementwise: value fp32 -> bf16 ----------------
__global__ void cvt_value_kernel(const float* __restrict__ in, u16* __restrict__ out, int n4) {
  int idx = blockIdx.x * blockDim.x + threadIdx.x;
  int stride = gridDim.x * blockDim.x;
  for (int i = idx; i < n4; i += stride) {
    f32x4 v = reinterpret_cast<const f32x4*>(in)[i];
    u16x4 o = { f2bf(v[0]), f2bf(v[1]), f2bf(v[2]), f2bf(v[3]) };
    reinterpret_cast<u16x4*>(out)[i] = o;
  }
}

// ---------------- mask + cast weights ----------------
// MODE 0: W1 (H x D),  keep col <= row%2047
// MODE 1: W2 (H x H),  keep col%2047 <= row%2047
// MODE 2: W3 (D x H),  keep row > col%2047
template<int MODE>
__global__ void mask_cvt_kernel(const float* __restrict__ in, u16* __restrict__ out, int n4) {
  const int shift = (MODE == 0) ? 11 : 12;
  const int cmask = (MODE == 0) ? 2047 : 4095;
  int idx0 = blockIdx.x * blockDim.x + threadIdx.x;
  int stride = gridDim.x * blockDim.x;
  for (int i = idx0; i < n4; i += stride) {
    int e0 = i * 4;
    int row = e0 >> shift;
    int col = e0 & cmask;
    int rdeg = row % 2047;
    f32x4 v = reinterpret_cast<const f32x4*>(in)[i];
    u16x4 o;
#pragma unroll
    for (int e = 0; e < 4; ++e) {
      int c = col + e;
      bool keep;
      if (MODE == 0)      keep = (c <= rdeg);
      else if (MODE == 1) keep = ((c % 2047) <= rdeg);
      else                keep = (row > (c % 2047));
      o[e] = keep ? f2bf(v[e]) : (u16)0;
    }
    reinterpret_cast<u16x4*>(out)[i] = o;
  }
}

// ---------------- GEMM: C(MxN) = A(MxK) * Bw(NxK)^T, bf16 MFMA ----------------
// EPI 0: C = relu(acc + bias)  stored as bf16
// EPI 1: logits = acc + bias; logprob terms reduced per row -> atomicAdd(outp)
// MASK 1: W1-triangular (skip k0 > rmax)
// MASK 2: W2 two-segment (skip blocks with min(k%2047) > rmax)
// MASK 3: W3 two-segment, rmax = bcol+126 (rows don't wrap)
// Column tiles are remapped LPT (heaviest-first): per-column work is monotone
// increasing over c=0..15 and c=16..31, so dispatch order 15,31,14,30,...
// puts full-K tiles first and near-empty tiles in the tail.
template<int EPI, int MASK>
__global__ __launch_bounds__(256) void gemm128_kernel(
    const u16* __restrict__ A,
    const u16* __restrict__ Bw,
    const float* __restrict__ bias,
    u16* __restrict__ C,
    const float* __restrict__ value,
    float* __restrict__ outp,
    int M, int N, int K)
{
  __shared__ u16 lsA[128 * 32];
  __shared__ u16 lsB[128 * 32];

  const int tid  = threadIdx.x;
  const int wave = tid >> 6;
  const int lane = tid & 63;
  const int wr = wave >> 1;     // wave row  (2x2 wave grid, each wave 64x64 out)
  const int wc = wave & 1;      // wave col
  const int l15 = lane & 15;
  const int lhi = lane >> 4;
  const int brow = blockIdx.y * 128;

  // LPT column remap (heaviest column tiles dispatch first)
  const int cx = blockIdx.x;
  const int ncx = gridDim.x;
  const int ctile = (ncx == 32) ? (((cx & 1) << 4) | (15 - (cx >> 1)))
                                : (ncx - 1 - cx);
  const int bcol = ctile * 128;

  // max needed hidden-degree index over this column tile (wave-uniform)
  int rmax;
  {
    int s = bcol, e = bcol + 127;
    if (MASK == 3) {
      rmax = bcol + 126;                 // keep k%2047 < r+1; max r = bcol+127
    } else {
      if (e <= 2046)      rmax = e;
      else if (s <= 2046) rmax = 2046;
      else {
        int em = e - 2047;
        rmax = (em <= 2046) ? em : 2046;
      }
    }
  }

  floatx4 acc[4][4];
#pragma unroll
  for (int i = 0; i < 4; ++i)
#pragma unroll
    for (int j = 0; j < 4; ++j)
      acc[i][j] = (floatx4){0.f, 0.f, 0.f, 0.f};

  // staging: 512 16B chunks per tile (128 rows x 64B), 2 per thread per tile
  const int ch0 = wave * 64 + lane;
  const int ch1 = ch0 + 256;
  const size_t aOff0 = (size_t)(brow + (ch0 >> 2)) * K + (ch0 & 3) * 8;
  const size_t aOff1 = (size_t)(brow + (ch1 >> 2)) * K + (ch1 & 3) * 8;
  const size_t bOff0 = (size_t)(bcol + (ch0 >> 2)) * K + (ch0 & 3) * 8;
  const size_t bOff1 = (size_t)(bcol + (ch1 >> 2)) * K + (ch1 & 3) * 8;
  u16* la0 = &lsA[ch0 * 8];
  u16* la1 = &lsA[ch1 * 8];
  u16* lb0 = &lsB[ch0 * 8];
  u16* lb1 = &lsB[ch1 * 8];

  for (int k0 = 0; k0 < K; k0 += 32) {
    // exact-zero-block skip (wave-uniform predicate)
    bool needed;
    if (MASK == 1) {
      needed = (k0 <= rmax);
      if (!needed) break;                // triangular: nothing needed past rmax
    } else {
      int m = (k0 >= 2047) ? (k0 - 2047) : k0;
      int mn = (m + 31 >= 2047) ? 0 : m;
      needed = (mn <= rmax);
    }
    if (!needed) continue;

    glds16(A  + aOff0 + k0, la0);
    glds16(A  + aOff1 + k0, la1);
    glds16(Bw + bOff0 + k0, lb0);
    glds16(Bw + bOff1 + k0, lb1);
    __syncthreads();

    short8 af[4], bfv[4];
#pragma unroll
    for (int mi = 0; mi < 4; ++mi)
      af[mi] = *(const short8*)&lsA[(wr * 64 + mi * 16 + l15) * 32 + lhi * 8];
#pragma unroll
    for (int ni = 0; ni < 4; ++ni)
      bfv[ni] = *(const short8*)&lsB[(wc * 64 + ni * 16 + l15) * 32 + lhi * 8];
#pragma unroll
    for (int mi = 0; mi < 4; ++mi)
#pragma unroll
      for (int ni = 0; ni < 4; ++ni)
        acc[mi][ni] = __builtin_amdgcn_mfma_f32_16x16x32_bf16(af[mi], bfv[ni], acc[mi][ni], 0, 0, 0);
    __syncthreads();
  }

  if (EPI == 0) {
#pragma unroll
    for (int mi = 0; mi < 4; ++mi) {
      int row = brow + wr * 64 + mi * 16 + lhi * 4;
#pragma unroll
      for (int ni = 0; ni < 4; ++ni) {
        int col = bcol + wc * 64 + ni * 16 + l15;
        float bv = bias[col];
#pragma unroll
        for (int e = 0; e < 4; ++e) {
          float v = acc[mi][ni][e] + bv;
          v = fmaxf(v, 0.0f);
          C[(size_t)(row + e) * N + col] = f2bf(v);
        }
      }
    }
  } else {
#pragma unroll
    for (int mi = 0; mi < 4; ++mi) {
#pragma unroll
      for (int e = 0; e < 4; ++e) {
        int row = brow + wr * 64 + mi * 16 + lhi * 4 + e;
        float partial = 0.0f;
#pragma unroll
        for (int ni = 0; ni < 4; ++ni) {
          int col = bcol + wc * 64 + ni * 16 + l15;
          float l = acc[mi][ni][e] + bias[col];
          float v = value[(size_t)row * N + col];
          float sp = fmaxf(l, 0.0f) + log1pf(__expf(-fabsf(l)));
          partial += v * l - sp;
        }
        // sum across the 16 lanes (l15 = 0..15) holding this row's 16 cols x 4 ni
#pragma unroll
        for (int off = 1; off < 16; off <<= 1)
          partial += __shfl_xor(partial, off, 64);
        if (l15 == 0) atomicAdd(&outp[row], partial);
      }
    }
  }
}

// ---------------- launcher ----------------
extern "C" void kernel_launch(void* const* d_in, const int* in_sizes, int n_in,
                              void* d_out, int out_size, void* d_ws, size_t ws_size,
                              hipStream_t stream) {
  const float* value = (const float*)d_in[0];
  const float* W1 = (const float*)d_in[1];
  const float* b1 = (const float*)d_in[2];
  const float* W2 = (const float*)d_in[3];
  const float* b2 = (const float*)d_in[4];
  const float* W3 = (const float*)d_in[5];
  const float* b3 = (const float*)d_in[6];
  float* out = (float*)d_out;

  char* ws = (char*)d_ws;
  // workspace layout (bytes)
  u16* vbf = (u16*)(ws);                        // B*D bf16   : 33,554,432
  u16* w1m = (u16*)(ws + 33554432ULL);          // H*D bf16   : 16,777,216
  u16* w2m = (u16*)(ws + 50331648ULL);          // H*H bf16   : 33,554,432
  u16* w3m = (u16*)(ws + 83886080ULL);          // D*H bf16   : 16,777,216
  u16* h1  = (u16*)(ws + 100663296ULL);         // B*H bf16   : 67,108,864
  u16* h2  = (u16*)(ws + 167772160ULL);         // B*H bf16   : 67,108,864
                                                // total      : ~224 MB

  hipMemsetAsync(d_out, 0, (size_t)out_size * sizeof(float), stream);

  cvt_value_kernel<<<2048, 256, 0, stream>>>(value, vbf, (BB * DD) / 4);
  mask_cvt_kernel<0><<<2048, 256, 0, stream>>>(W1, w1m, (HH * DD) / 4);
  mask_cvt_kernel<1><<<2048, 256, 0, stream>>>(W2, w2m, (HH * HH) / 4);
  mask_cvt_kernel<2><<<2048, 256, 0, stream>>>(W3, w3m, (DD * HH) / 4);

  dim3 g12(HH / 128, BB / 128);
  gemm128_kernel<0, 1><<<g12, 256, 0, stream>>>(vbf, w1m, b1, h1, nullptr, nullptr, BB, HH, DD);
  gemm128_kernel<0, 2><<<g12, 256, 0, stream>>>(h1, w2m, b2, h2, nullptr, nullptr, BB, HH, HH);
  dim3 g3(DD / 128, BB / 128);
  gemm128_kernel<1, 3><<<g3, 256, 0, stream>>>(h2, w3m, b3, nullptr, value, out, BB, DD, HH);
}

// Round 4
// 556.623 us; speedup vs baseline: 1.4310x; 1.4310x over previous
//
#include <hip/hip_runtime.h>
#include <hip/hip_bf16.h>
#include <cstdint>

typedef short short8 __attribute__((ext_vector_type(8)));
typedef float floatx4 __attribute__((ext_vector_type(4)));
typedef float f32x4 __attribute__((ext_vector_type(4)));
typedef unsigned short u16;
typedef unsigned short u16x4 __attribute__((ext_vector_type(4)));

#define BB 8192
#define DD 2048
#define HH 4096

static __device__ __forceinline__ u16 f2bf(float x) {
  __hip_bfloat16 h = __float2bfloat16(x);
  return __builtin_bit_cast(u16, h);
}

static __device__ __forceinline__ void glds16(const u16* g, u16* l) {
  __builtin_amdgcn_global_load_lds(
      (const __attribute__((address_space(1))) void*)g,
      (__attribute__((address_space(3))) void*)l, 16, 0, 0);
}

// ---------------- elementwise: value fp32 -> bf16 ----------------
__global__ void cvt_value_kernel(const float* __restrict__ in, u16* __restrict__ out, int n4) {
  int idx = blockIdx.x * blockDim.x + threadIdx.x;
  int stride = gridDim.x * blockDim.x;
  for (int i = idx; i < n4; i += stride) {
    f32x4 v = reinterpret_cast<const f32x4*>(in)[i];
    u16x4 o = { f2bf(v[0]), f2bf(v[1]), f2bf(v[2]), f2bf(v[3]) };
    reinterpret_cast<u16x4*>(out)[i] = o;
  }
}

// ---------------- mask + cast weights ----------------
// MODE 0: W1 (H x D),  keep col <= row%2047
// MODE 1: W2 (H x H),  keep col%2047 <= row%2047
// MODE 2: W3 (D x H),  keep row > col%2047
template<int MODE>
__global__ void mask_cvt_kernel(const float* __restrict__ in, u16* __restrict__ out, int n4) {
  const int shift = (MODE == 0) ? 11 : 12;
  const int cmask = (MODE == 0) ? 2047 : 4095;
  int idx0 = blockIdx.x * blockDim.x + threadIdx.x;
  int stride = gridDim.x * blockDim.x;
  for (int i = idx0; i < n4; i += stride) {
    int e0 = i * 4;
    int row = e0 >> shift;
    int col = e0 & cmask;
    int rdeg = row % 2047;
    f32x4 v = reinterpret_cast<const f32x4*>(in)[i];
    u16x4 o;
#pragma unroll
    for (int e = 0; e < 4; ++e) {
      int c = col + e;
      bool keep;
      if (MODE == 0)      keep = (c <= rdeg);
      else if (MODE == 1) keep = ((c % 2047) <= rdeg);
      else                keep = (row > (c % 2047));
      o[e] = keep ? f2bf(v[e]) : (u16)0;
    }
    reinterpret_cast<u16x4*>(out)[i] = o;
  }
}

// ---------------- GEMM: C(MxN) = A(MxK) * Bw(NxK)^T, bf16 MFMA ----------------
// EPI 0: C = relu(acc + bias)  stored as bf16
// EPI 1: logits = acc + bias; logprob terms reduced per row -> atomicAdd(outp)
// MASK 1: W1-triangular (skip k0 > rmax)
// MASK 2: W2 two-segment (skip blocks with min(k%2047) > rmax)
// MASK 3: W3 two-segment, rmax = bcol+126 (rows don't wrap)
//
// WORK BALANCE: per-column-tile K-block count is affine in q=c%16
// (G1: 4q+4, G2: ~8q+9, G3: ~8c+9), so each block processes the PAIR
// {q, 15-q} (same 128-row strip) -> every block has identical work,
// occupancy stays flat, latency hiding is preserved while doing 0.53x
// the dense iterations. Grid: G1/G2 16x64, G3 8x64.
template<int EPI, int MASK>
__global__ __launch_bounds__(256) void gemm128_kernel(
    const u16* __restrict__ A,
    const u16* __restrict__ Bw,
    const float* __restrict__ bias,
    u16* __restrict__ C,
    const float* __restrict__ value,
    float* __restrict__ outp,
    int M, int N, int K)
{
  __shared__ u16 lsA[128 * 32];
  __shared__ u16 lsB[128 * 32];

  const int tid  = threadIdx.x;
  const int wave = tid >> 6;
  const int lane = tid & 63;
  const int wr = wave >> 1;     // wave row  (2x2 wave grid, each wave 64x64 out)
  const int wc = wave & 1;      // wave col
  const int l15 = lane & 15;
  const int lhi = lane >> 4;
  const int brow = blockIdx.y * 128;

  // balanced column-tile pair for this block
  const int p = blockIdx.x;
  int cols[2];
  if (gridDim.x == 16) {               // 32-column GEMMs (G1, G2)
    cols[0] = (p < 8) ? p : p + 8;     // q      in its 16-col half
    cols[1] = (p < 8) ? 15 - p : 39 - p; // 15-q  in the same half
  } else {                             // 16-column GEMM (G3)
    cols[0] = p;
    cols[1] = 15 - p;
  }

  // staging: 512 16B chunks per tile (128 rows x 64B), 2 per thread per tile
  const int ch0 = wave * 64 + lane;
  const int ch1 = ch0 + 256;
  const size_t aOff0 = (size_t)(brow + (ch0 >> 2)) * K + (ch0 & 3) * 8;
  const size_t aOff1 = (size_t)(brow + (ch1 >> 2)) * K + (ch1 & 3) * 8;
  u16* la0 = &lsA[ch0 * 8];
  u16* la1 = &lsA[ch1 * 8];
  u16* lb0 = &lsB[ch0 * 8];
  u16* lb1 = &lsB[ch1 * 8];

#pragma unroll
  for (int t = 0; t < 2; ++t) {
    const int bcol = cols[t] * 128;

    // max needed hidden-degree index over this column tile (wave-uniform)
    int rmax;
    {
      int s = bcol, e = bcol + 127;
      if (MASK == 3) {
        rmax = bcol + 126;               // keep k%2047 < r+1; max r = bcol+127
      } else {
        if (e <= 2046)      rmax = e;
        else if (s <= 2046) rmax = 2046;
        else {
          int em = e - 2047;
          rmax = (em <= 2046) ? em : 2046;
        }
      }
    }

    const size_t bOff0 = (size_t)(bcol + (ch0 >> 2)) * K + (ch0 & 3) * 8;
    const size_t bOff1 = (size_t)(bcol + (ch1 >> 2)) * K + (ch1 & 3) * 8;

    floatx4 acc[4][4];
#pragma unroll
    for (int i = 0; i < 4; ++i)
#pragma unroll
      for (int j = 0; j < 4; ++j)
        acc[i][j] = (floatx4){0.f, 0.f, 0.f, 0.f};

    for (int k0 = 0; k0 < K; k0 += 32) {
      // exact-zero-block skip (wave-uniform predicate)
      bool needed;
      if (MASK == 1) {
        needed = (k0 <= rmax);
        if (!needed) break;              // triangular: nothing needed past rmax
      } else {
        int m = (k0 >= 2047) ? (k0 - 2047) : k0;
        int mn = (m + 31 >= 2047) ? 0 : m;
        needed = (mn <= rmax);
      }
      if (!needed) continue;

      glds16(A  + aOff0 + k0, la0);
      glds16(A  + aOff1 + k0, la1);
      glds16(Bw + bOff0 + k0, lb0);
      glds16(Bw + bOff1 + k0, lb1);
      __syncthreads();

      short8 af[4], bfv[4];
#pragma unroll
      for (int mi = 0; mi < 4; ++mi)
        af[mi] = *(const short8*)&lsA[(wr * 64 + mi * 16 + l15) * 32 + lhi * 8];
#pragma unroll
      for (int ni = 0; ni < 4; ++ni)
        bfv[ni] = *(const short8*)&lsB[(wc * 64 + ni * 16 + l15) * 32 + lhi * 8];
#pragma unroll
      for (int mi = 0; mi < 4; ++mi)
#pragma unroll
        for (int ni = 0; ni < 4; ++ni)
          acc[mi][ni] = __builtin_amdgcn_mfma_f32_16x16x32_bf16(af[mi], bfv[ni], acc[mi][ni], 0, 0, 0);
      __syncthreads();
    }

    if (EPI == 0) {
#pragma unroll
      for (int mi = 0; mi < 4; ++mi) {
        int row = brow + wr * 64 + mi * 16 + lhi * 4;
#pragma unroll
        for (int ni = 0; ni < 4; ++ni) {
          int col = bcol + wc * 64 + ni * 16 + l15;
          float bv = bias[col];
#pragma unroll
          for (int e = 0; e < 4; ++e) {
            float v = acc[mi][ni][e] + bv;
            v = fmaxf(v, 0.0f);
            C[(size_t)(row + e) * N + col] = f2bf(v);
          }
        }
      }
    } else {
#pragma unroll
      for (int mi = 0; mi < 4; ++mi) {
#pragma unroll
        for (int e = 0; e < 4; ++e) {
          int row = brow + wr * 64 + mi * 16 + lhi * 4 + e;
          float partial = 0.0f;
#pragma unroll
          for (int ni = 0; ni < 4; ++ni) {
            int col = bcol + wc * 64 + ni * 16 + l15;
            float l = acc[mi][ni][e] + bias[col];
            float v = value[(size_t)row * N + col];
            float sp = fmaxf(l, 0.0f) + log1pf(__expf(-fabsf(l)));
            partial += v * l - sp;
          }
          // sum across the 16 lanes (l15 = 0..15) holding this row's cols
#pragma unroll
          for (int off = 1; off < 16; off <<= 1)
            partial += __shfl_xor(partial, off, 64);
          if (l15 == 0) atomicAdd(&outp[row], partial);
        }
      }
    }
  }
}

// ---------------- launcher ----------------
extern "C" void kernel_launch(void* const* d_in, const int* in_sizes, int n_in,
                              void* d_out, int out_size, void* d_ws, size_t ws_size,
                              hipStream_t stream) {
  const float* value = (const float*)d_in[0];
  const float* W1 = (const float*)d_in[1];
  const float* b1 = (const float*)d_in[2];
  const float* W2 = (const float*)d_in[3];
  const float* b2 = (const float*)d_in[4];
  const float* W3 = (const float*)d_in[5];
  const float* b3 = (const float*)d_in[6];
  float* out = (float*)d_out;

  char* ws = (char*)d_ws;
  // workspace layout (bytes)
  u16* vbf = (u16*)(ws);                        // B*D bf16   : 33,554,432
  u16* w1m = (u16*)(ws + 33554432ULL);          // H*D bf16   : 16,777,216
  u16* w2m = (u16*)(ws + 50331648ULL);          // H*H bf16   : 33,554,432
  u16* w3m = (u16*)(ws + 83886080ULL);          // D*H bf16   : 16,777,216
  u16* h1  = (u16*)(ws + 100663296ULL);         // B*H bf16   : 67,108,864
  u16* h2  = (u16*)(ws + 167772160ULL);         // B*H bf16   : 67,108,864
                                                // total      : ~224 MB

  hipMemsetAsync(d_out, 0, (size_t)out_size * sizeof(float), stream);

  cvt_value_kernel<<<2048, 256, 0, stream>>>(value, vbf, (BB * DD) / 4);
  mask_cvt_kernel<0><<<2048, 256, 0, stream>>>(W1, w1m, (HH * DD) / 4);
  mask_cvt_kernel<1><<<2048, 256, 0, stream>>>(W2, w2m, (HH * HH) / 4);
  mask_cvt_kernel<2><<<2048, 256, 0, stream>>>(W3, w3m, (DD * HH) / 4);

  dim3 g12(16, BB / 128);
  gemm128_kernel<0, 1><<<g12, 256, 0, stream>>>(vbf, w1m, b1, h1, nullptr, nullptr, BB, HH, DD);
  gemm128_kernel<0, 2><<<g12, 256, 0, stream>>>(h1, w2m, b2, h2, nullptr, nullptr, BB, HH, HH);
  dim3 g3(8, BB / 128);
  gemm128_kernel<1, 3><<<g3, 256, 0, stream>>>(h2, w3m, b3, nullptr, value, out, BB, DD, HH);
}

// Round 5
// 527.696 us; speedup vs baseline: 1.5094x; 1.0548x over previous
//
#include <hip/hip_runtime.h>
#include <hip/hip_bf16.h>
#include <cstdint>

typedef short short8 __attribute__((ext_vector_type(8)));
typedef float floatx4 __attribute__((ext_vector_type(4)));
typedef float f32x4 __attribute__((ext_vector_type(4)));
typedef unsigned short u16;
typedef unsigned short u16x4 __attribute__((ext_vector_type(4)));

#define BB 8192
#define DD 2048
#define HH 4096

static __device__ __forceinline__ u16 f2bf(float x) {
  __hip_bfloat16 h = __float2bfloat16(x);
  return __builtin_bit_cast(u16, h);
}

static __device__ __forceinline__ void glds16(const u16* g, u16* l) {
  __builtin_amdgcn_global_load_lds(
      (const __attribute__((address_space(1))) void*)g,
      (__attribute__((address_space(3))) void*)l, 16, 0, 0);
}

// ---------------- elementwise: value fp32 -> bf16 ----------------
__global__ void cvt_value_kernel(const float* __restrict__ in, u16* __restrict__ out, int n4) {
  int idx = blockIdx.x * blockDim.x + threadIdx.x;
  int stride = gridDim.x * blockDim.x;
  for (int i = idx; i < n4; i += stride) {
    f32x4 v = reinterpret_cast<const f32x4*>(in)[i];
    u16x4 o = { f2bf(v[0]), f2bf(v[1]), f2bf(v[2]), f2bf(v[3]) };
    reinterpret_cast<u16x4*>(out)[i] = o;
  }
}

// ---------------- mask + cast weights ----------------
// MODE 0: W1 (H x D),  keep col <= row%2047
// MODE 1: W2 (H x H),  keep col%2047 <= row%2047
// MODE 2: W3 (D x H),  keep row > col%2047
template<int MODE>
__global__ void mask_cvt_kernel(const float* __restrict__ in, u16* __restrict__ out, int n4) {
  const int shift = (MODE == 0) ? 11 : 12;
  const int cmask = (MODE == 0) ? 2047 : 4095;
  int idx0 = blockIdx.x * blockDim.x + threadIdx.x;
  int stride = gridDim.x * blockDim.x;
  for (int i = idx0; i < n4; i += stride) {
    int e0 = i * 4;
    int row = e0 >> shift;
    int col = e0 & cmask;
    int rdeg = row % 2047;
    f32x4 v = reinterpret_cast<const f32x4*>(in)[i];
    u16x4 o;
#pragma unroll
    for (int e = 0; e < 4; ++e) {
      int c = col + e;
      bool keep;
      if (MODE == 0)      keep = (c <= rdeg);
      else if (MODE == 1) keep = ((c % 2047) <= rdeg);
      else                keep = (row > (c % 2047));
      o[e] = keep ? f2bf(v[e]) : (u16)0;
    }
    reinterpret_cast<u16x4*>(out)[i] = o;
  }
}

// ---------------- GEMM: C(MxN) = A(MxK) * Bw(NxK)^T, bf16 MFMA ----------------
// EPI 0: C = relu(acc + bias)  stored as bf16
// EPI 1: logits = acc + bias; logprob terms reduced per row -> atomicAdd(outp)
// MASK 1: W1-triangular (skip k0 > rmax)
// MASK 2: W2 two-segment (skip blocks with min(k%2047) > rmax)
// MASK 3: W3 two-segment, rmax = bcol+126 (rows don't wrap)
// BM: block row-tile height (128 or 64). Column tile is always 128.
//   BM=64 doubles the grid (4 blocks/CU) for latency hiding on the
//   grid-limited GEMM3.
//
// WORK BALANCE: per-column-tile K-block count is affine in q=c%16, so each
// block processes the PAIR {q, 15-q} within its 16-col half -> identical
// work per block. Grid: G1/G2 16x64 (BM=128), G3 8x128 (BM=64).
template<int EPI, int MASK, int BM>
__global__ __launch_bounds__(256) void gemm_kernel(
    const u16* __restrict__ A,
    const u16* __restrict__ Bw,
    const float* __restrict__ bias,
    u16* __restrict__ C,
    const float* __restrict__ value,
    float* __restrict__ outp,
    int M, int N, int K)
{
  constexpr int MI = BM / 32;          // acc fragments per wave in M (4 or 2)
  __shared__ u16 lsA[BM * 32];
  __shared__ u16 lsB[128 * 32];

  const int tid  = threadIdx.x;
  const int wave = tid >> 6;
  const int lane = tid & 63;
  const int wr = wave >> 1;     // 2x2 wave grid; wave tile = (BM/2) x 64
  const int wc = wave & 1;
  const int l15 = lane & 15;
  const int lhi = lane >> 4;
  const int brow = blockIdx.y * BM;

  // balanced column-tile pair for this block
  const int p = blockIdx.x;
  int cols[2];
  if (gridDim.x == 16) {                 // 32-column GEMMs (G1, G2)
    cols[0] = (p < 8) ? p : p + 8;       // q     in its 16-col half
    cols[1] = (p < 8) ? 15 - p : 39 - p; // 15-q  in the same half
  } else {                               // 16-column GEMM (G3)
    cols[0] = p;
    cols[1] = 15 - p;
  }

  // staging chunk ids (16B each); A has BM*4 chunks, B has 512 chunks
  const int ch0 = wave * 64 + lane;      // 0..255
  const int ch1 = ch0 + 256;
  const size_t aOff0 = (size_t)(brow + (ch0 >> 2)) * K + (ch0 & 3) * 8;
  u16* la0 = &lsA[ch0 * 8];
  size_t aOff1 = 0; u16* la1 = nullptr;
  if constexpr (BM == 128) {
    aOff1 = (size_t)(brow + (ch1 >> 2)) * K + (ch1 & 3) * 8;
    la1 = &lsA[ch1 * 8];
  }
  u16* lb0 = &lsB[ch0 * 8];
  u16* lb1 = &lsB[ch1 * 8];

#pragma unroll
  for (int t = 0; t < 2; ++t) {
    const int bcol = cols[t] * 128;

    // max needed hidden-degree index over this column tile (wave-uniform)
    int rmax;
    {
      int s = bcol, e = bcol + 127;
      if (MASK == 3) {
        rmax = bcol + 126;               // keep k%2047 < r+1; max r = bcol+127
      } else {
        if (e <= 2046)      rmax = e;
        else if (s <= 2046) rmax = 2046;
        else {
          int em = e - 2047;
          rmax = (em <= 2046) ? em : 2046;
        }
      }
    }

    const size_t bOff0 = (size_t)(bcol + (ch0 >> 2)) * K + (ch0 & 3) * 8;
    const size_t bOff1 = (size_t)(bcol + (ch1 >> 2)) * K + (ch1 & 3) * 8;

    floatx4 acc[MI][4];
#pragma unroll
    for (int i = 0; i < MI; ++i)
#pragma unroll
      for (int j = 0; j < 4; ++j)
        acc[i][j] = (floatx4){0.f, 0.f, 0.f, 0.f};

    for (int k0 = 0; k0 < K; k0 += 32) {
      // exact-zero-block skip (wave-uniform predicate)
      bool needed;
      if (MASK == 1) {
        needed = (k0 <= rmax);
        if (!needed) break;              // triangular: nothing needed past rmax
      } else {
        int m = (k0 >= 2047) ? (k0 - 2047) : k0;
        int mn = (m + 31 >= 2047) ? 0 : m;
        needed = (mn <= rmax);
      }
      if (!needed) continue;

      glds16(A + aOff0 + k0, la0);
      if constexpr (BM == 128) glds16(A + aOff1 + k0, la1);
      glds16(Bw + bOff0 + k0, lb0);
      glds16(Bw + bOff1 + k0, lb1);
      __syncthreads();

      short8 af[MI], bfv[4];
#pragma unroll
      for (int mi = 0; mi < MI; ++mi)
        af[mi] = *(const short8*)&lsA[(wr * (BM / 2) + mi * 16 + l15) * 32 + lhi * 8];
#pragma unroll
      for (int ni = 0; ni < 4; ++ni)
        bfv[ni] = *(const short8*)&lsB[(wc * 64 + ni * 16 + l15) * 32 + lhi * 8];
#pragma unroll
      for (int mi = 0; mi < MI; ++mi)
#pragma unroll
        for (int ni = 0; ni < 4; ++ni)
          acc[mi][ni] = __builtin_amdgcn_mfma_f32_16x16x32_bf16(af[mi], bfv[ni], acc[mi][ni], 0, 0, 0);
      __syncthreads();
    }

    if (EPI == 0) {
#pragma unroll
      for (int mi = 0; mi < MI; ++mi) {
        int row = brow + wr * (BM / 2) + mi * 16 + lhi * 4;
#pragma unroll
        for (int ni = 0; ni < 4; ++ni) {
          int col = bcol + wc * 64 + ni * 16 + l15;
          float bv = bias[col];
#pragma unroll
          for (int e = 0; e < 4; ++e) {
            float v = acc[mi][ni][e] + bv;
            v = fmaxf(v, 0.0f);
            C[(size_t)(row + e) * N + col] = f2bf(v);
          }
        }
      }
    } else {
#pragma unroll
      for (int mi = 0; mi < MI; ++mi) {
#pragma unroll
        for (int e = 0; e < 4; ++e) {
          int row = brow + wr * (BM / 2) + mi * 16 + lhi * 4 + e;
          float partial = 0.0f;
#pragma unroll
          for (int ni = 0; ni < 4; ++ni) {
            int col = bcol + wc * 64 + ni * 16 + l15;
            float l = acc[mi][ni][e] + bias[col];
            float v = value[(size_t)row * N + col];
            // softplus(l) = max(l,0) + log(1 + exp(-|l|)); __logf is exact
            // enough here (abs err ~1e-6 vs threshold 28.5)
            float sp = fmaxf(l, 0.0f) + __logf(1.0f + __expf(-fabsf(l)));
            partial += v * l - sp;
          }
          // sum across the 16 lanes (l15 = 0..15) holding this row's cols
#pragma unroll
          for (int off = 1; off < 16; off <<= 1)
            partial += __shfl_xor(partial, off, 64);
          if (l15 == 0) atomicAdd(&outp[row], partial);
        }
      }
    }
  }
}

// ---------------- launcher ----------------
extern "C" void kernel_launch(void* const* d_in, const int* in_sizes, int n_in,
                              void* d_out, int out_size, void* d_ws, size_t ws_size,
                              hipStream_t stream) {
  const float* value = (const float*)d_in[0];
  const float* W1 = (const float*)d_in[1];
  const float* b1 = (const float*)d_in[2];
  const float* W2 = (const float*)d_in[3];
  const float* b2 = (const float*)d_in[4];
  const float* W3 = (const float*)d_in[5];
  const float* b3 = (const float*)d_in[6];
  float* out = (float*)d_out;

  char* ws = (char*)d_ws;
  // workspace layout (bytes)
  u16* vbf = (u16*)(ws);                        // B*D bf16   : 33,554,432
  u16* w1m = (u16*)(ws + 33554432ULL);          // H*D bf16   : 16,777,216
  u16* w2m = (u16*)(ws + 50331648ULL);          // H*H bf16   : 33,554,432
  u16* w3m = (u16*)(ws + 83886080ULL);          // D*H bf16   : 16,777,216
  u16* h1  = (u16*)(ws + 100663296ULL);         // B*H bf16   : 67,108,864
  u16* h2  = (u16*)(ws + 167772160ULL);         // B*H bf16   : 67,108,864
                                                // total      : ~224 MB

  hipMemsetAsync(d_out, 0, (size_t)out_size * sizeof(float), stream);

  cvt_value_kernel<<<2048, 256, 0, stream>>>(value, vbf, (BB * DD) / 4);
  mask_cvt_kernel<0><<<2048, 256, 0, stream>>>(W1, w1m, (HH * DD) / 4);
  mask_cvt_kernel<1><<<2048, 256, 0, stream>>>(W2, w2m, (HH * HH) / 4);
  mask_cvt_kernel<2><<<2048, 256, 0, stream>>>(W3, w3m, (DD * HH) / 4);

  dim3 g12(16, BB / 128);
  gemm_kernel<0, 1, 128><<<g12, 256, 0, stream>>>(vbf, w1m, b1, h1, nullptr, nullptr, BB, HH, DD);
  gemm_kernel<0, 2, 128><<<g12, 256, 0, stream>>>(h1, w2m, b2, h2, nullptr, nullptr, BB, HH, HH);
  dim3 g3(8, BB / 64);
  gemm_kernel<1, 3, 64><<<g3, 256, 0, stream>>>(h2, w3m, b3, nullptr, value, out, BB, DD, HH);
}

// Round 6
// 469.664 us; speedup vs baseline: 1.6959x; 1.1236x over previous
//
#include <hip/hip_runtime.h>
#include <hip/hip_bf16.h>
#include <cstdint>

typedef short short8 __attribute__((ext_vector_type(8)));
typedef float floatx4 __attribute__((ext_vector_type(4)));
typedef float f32x4 __attribute__((ext_vector_type(4)));
typedef unsigned short u16;
typedef unsigned short u16x4 __attribute__((ext_vector_type(4)));

#define BB 8192
#define DD 2048
#define HH 4096

static __device__ __forceinline__ u16 f2bf(float x) {
  __hip_bfloat16 h = __float2bfloat16(x);
  return __builtin_bit_cast(u16, h);
}

static __device__ __forceinline__ void glds16(const u16* g, u16* l) {
  __builtin_amdgcn_global_load_lds(
      (const __attribute__((address_space(1))) void*)g,
      (__attribute__((address_space(3))) void*)l, 16, 0, 0);
}

// ---------------- elementwise: value fp32 -> bf16 ----------------
__global__ void cvt_value_kernel(const float* __restrict__ in, u16* __restrict__ out, int n4) {
  int idx = blockIdx.x * blockDim.x + threadIdx.x;
  int stride = gridDim.x * blockDim.x;
  for (int i = idx; i < n4; i += stride) {
    f32x4 v = reinterpret_cast<const f32x4*>(in)[i];
    u16x4 o = { f2bf(v[0]), f2bf(v[1]), f2bf(v[2]), f2bf(v[3]) };
    reinterpret_cast<u16x4*>(out)[i] = o;
  }
}

// ---------------- mask + cast weights ----------------
// MODE 0: W1 (H x D),  keep col <= row%2047
// MODE 1: W2 (H x H),  keep col%2047 <= row%2047
// MODE 2: W3 (D x H),  keep row > col%2047
template<int MODE>
__global__ void mask_cvt_kernel(const float* __restrict__ in, u16* __restrict__ out, int n4) {
  const int shift = (MODE == 0) ? 11 : 12;
  const int cmask = (MODE == 0) ? 2047 : 4095;
  int idx0 = blockIdx.x * blockDim.x + threadIdx.x;
  int stride = gridDim.x * blockDim.x;
  for (int i = idx0; i < n4; i += stride) {
    int e0 = i * 4;
    int row = e0 >> shift;
    int col = e0 & cmask;
    int rdeg = row % 2047;
    f32x4 v = reinterpret_cast<const f32x4*>(in)[i];
    u16x4 o;
#pragma unroll
    for (int e = 0; e < 4; ++e) {
      int c = col + e;
      bool keep;
      if (MODE == 0)      keep = (c <= rdeg);
      else if (MODE == 1) keep = ((c % 2047) <= rdeg);
      else                keep = (row > (c % 2047));
      o[e] = keep ? f2bf(v[e]) : (u16)0;
    }
    reinterpret_cast<u16x4*>(out)[i] = o;
  }
}

// ---------------- GEMM: C(MxN) = A(MxK) * Bw(NxK)^T, bf16 MFMA ----------------
// BK=64: 32 MFMA per barrier pair (two k-slices of 16), halving barrier drains.
// LDS tiles are [rows][64] bf16 (128B row stride). To avoid the 16-way bank
// conflict on ds_read_b128, rows are XOR-swizzled (chunk ^= row&7) — applied
// on the GLOBAL source address (global_load_lds dest must stay linear,
// rule #21) and identically on the read address. Exact data movement.
//
// EPI 0: C = relu(acc + bias)  stored as bf16
// EPI 1: logits = acc + bias; logprob reduced per row -> atomicAdd(outp)
// MASK 1: W1-triangular; MASK 2: W2 two-segment; MASK 3: W3 two-segment
// WORK BALANCE: block processes column-tile PAIR {q, 15-q} (equal work/block).
template<int EPI, int MASK, int BM>
__global__ __launch_bounds__(256) void gemm_kernel(
    const u16* __restrict__ A,
    const u16* __restrict__ Bw,
    const float* __restrict__ bias,
    u16* __restrict__ C,
    const float* __restrict__ value,
    float* __restrict__ outp,
    int M, int N, int K)
{
  constexpr int MI  = BM / 32;        // acc fragments per wave in M (4 or 2)
  constexpr int APT = BM / 32;        // A 16B-chunks per thread (BM*8/256)
  __shared__ u16 lsA[BM * 64];
  __shared__ u16 lsB[128 * 64];

  const int tid  = threadIdx.x;
  const int wave = tid >> 6;
  const int lane = tid & 63;
  const int wr = wave >> 1;     // 2x2 wave grid; wave tile = (BM/2) x 64
  const int wc = wave & 1;
  const int l15 = lane & 15;
  const int lhi = lane >> 4;
  const int brow = blockIdx.y * BM;

  // balanced column-tile pair for this block
  const int p = blockIdx.x;
  int cols[2];
  if (gridDim.x == 16) {                 // 32-column GEMMs (G1, G2)
    cols[0] = (p < 8) ? p : p + 8;       // q     in its 16-col half
    cols[1] = (p < 8) ? 15 - p : 39 - p; // 15-q  in the same half
  } else {                               // 16-column GEMM (G3)
    cols[0] = p;
    cols[1] = 15 - p;
  }

  // ---- staging descriptors (16B chunks; row = ch>>3, sub = ch&7) ----
  // global source chunk is XOR-swizzled: ssub = sub ^ (row&7); LDS dest linear.
  size_t aOff[APT]; u16* aDst[APT];
#pragma unroll
  for (int t = 0; t < APT; ++t) {
    int ch = tid + 256 * t;
    int row = ch >> 3, sub = ch & 7;
    int ssub = sub ^ (row & 7);
    aOff[t] = (size_t)(brow + row) * K + ssub * 8;
    aDst[t] = &lsA[ch * 8];
  }
  int bRow[4], bSsub[4]; u16* bDst[4];
#pragma unroll
  for (int t = 0; t < 4; ++t) {
    int ch = tid + 256 * t;
    int row = ch >> 3, sub = ch & 7;
    bRow[t] = row;
    bSsub[t] = sub ^ (row & 7);
    bDst[t] = &lsB[ch * 8];
  }

#pragma unroll
  for (int t = 0; t < 2; ++t) {
    const int bcol = cols[t] * 128;

    // max needed hidden-degree index over this column tile (wave-uniform)
    int rmax;
    {
      int s = bcol, e = bcol + 127;
      if (MASK == 3) {
        rmax = bcol + 126;               // keep k%2047 <= r-1; max r = bcol+127
      } else {
        if (e <= 2046)      rmax = e;
        else if (s <= 2046) rmax = 2046;
        else {
          int em = e - 2047;
          rmax = (em <= 2046) ? em : 2046;
        }
      }
    }

    size_t bOff[4];
#pragma unroll
    for (int u = 0; u < 4; ++u)
      bOff[u] = (size_t)(bcol + bRow[u]) * K + bSsub[u] * 8;

    floatx4 acc[MI][4];
#pragma unroll
    for (int i = 0; i < MI; ++i)
#pragma unroll
      for (int j = 0; j < 4; ++j)
        acc[i][j] = (floatx4){0.f, 0.f, 0.f, 0.f};

    for (int k0 = 0; k0 < K; k0 += 64) {
      // exact-zero 64-tile skip (wave-uniform predicate)
      bool needed;
      if (MASK == 1) {
        needed = (k0 <= rmax);
        if (!needed) break;              // triangular: nothing past rmax
      } else {
        int m = (k0 >= 2047) ? (k0 - 2047) : k0;
        int mn = (m + 63 >= 2047) ? 0 : m;
        needed = (mn <= rmax);
      }
      if (!needed) continue;

#pragma unroll
      for (int u = 0; u < APT; ++u) glds16(A + aOff[u] + k0, aDst[u]);
#pragma unroll
      for (int u = 0; u < 4; ++u)   glds16(Bw + bOff[u] + k0, bDst[u]);
      __syncthreads();

#pragma unroll
      for (int ks = 0; ks < 2; ++ks) {
        short8 af[MI], bfv[4];
#pragma unroll
        for (int mi = 0; mi < MI; ++mi) {
          int row = wr * (BM / 2) + mi * 16 + l15;
          af[mi] = *(const short8*)&lsA[row * 64 + (((ks * 4 + lhi) ^ (row & 7)) * 8)];
        }
#pragma unroll
        for (int ni = 0; ni < 4; ++ni) {
          int row = wc * 64 + ni * 16 + l15;
          bfv[ni] = *(const short8*)&lsB[row * 64 + (((ks * 4 + lhi) ^ (row & 7)) * 8)];
        }
#pragma unroll
        for (int mi = 0; mi < MI; ++mi)
#pragma unroll
          for (int ni = 0; ni < 4; ++ni)
            acc[mi][ni] = __builtin_amdgcn_mfma_f32_16x16x32_bf16(af[mi], bfv[ni], acc[mi][ni], 0, 0, 0);
      }
      __syncthreads();
    }

    if (EPI == 0) {
#pragma unroll
      for (int mi = 0; mi < MI; ++mi) {
        int row = brow + wr * (BM / 2) + mi * 16 + lhi * 4;
#pragma unroll
        for (int ni = 0; ni < 4; ++ni) {
          int col = bcol + wc * 64 + ni * 16 + l15;
          float bv = bias[col];
#pragma unroll
          for (int e = 0; e < 4; ++e) {
            float v = acc[mi][ni][e] + bv;
            v = fmaxf(v, 0.0f);
            C[(size_t)(row + e) * N + col] = f2bf(v);
          }
        }
      }
    } else {
#pragma unroll
      for (int mi = 0; mi < MI; ++mi) {
#pragma unroll
        for (int e = 0; e < 4; ++e) {
          int row = brow + wr * (BM / 2) + mi * 16 + lhi * 4 + e;
          float partial = 0.0f;
#pragma unroll
          for (int ni = 0; ni < 4; ++ni) {
            int col = bcol + wc * 64 + ni * 16 + l15;
            float l = acc[mi][ni][e] + bias[col];
            float v = value[(size_t)row * N + col];
            float sp = fmaxf(l, 0.0f) + __logf(1.0f + __expf(-fabsf(l)));
            partial += v * l - sp;
          }
#pragma unroll
          for (int off = 1; off < 16; off <<= 1)
            partial += __shfl_xor(partial, off, 64);
          if (l15 == 0) atomicAdd(&outp[row], partial);
        }
      }
    }
  }
}

// ---------------- launcher ----------------
extern "C" void kernel_launch(void* const* d_in, const int* in_sizes, int n_in,
                              void* d_out, int out_size, void* d_ws, size_t ws_size,
                              hipStream_t stream) {
  const float* value = (const float*)d_in[0];
  const float* W1 = (const float*)d_in[1];
  const float* b1 = (const float*)d_in[2];
  const float* W2 = (const float*)d_in[3];
  const float* b2 = (const float*)d_in[4];
  const float* W3 = (const float*)d_in[5];
  const float* b3 = (const float*)d_in[6];
  float* out = (float*)d_out;

  char* ws = (char*)d_ws;
  // workspace layout (bytes)
  u16* vbf = (u16*)(ws);                        // B*D bf16   : 33,554,432
  u16* w1m = (u16*)(ws + 33554432ULL);          // H*D bf16   : 16,777,216
  u16* w2m = (u16*)(ws + 50331648ULL);          // H*H bf16   : 33,554,432
  u16* w3m = (u16*)(ws + 83886080ULL);          // D*H bf16   : 16,777,216
  u16* h1  = (u16*)(ws + 100663296ULL);         // B*H bf16   : 67,108,864
  u16* h2  = (u16*)(ws + 167772160ULL);         // B*H bf16   : 67,108,864
                                                // total      : ~224 MB

  hipMemsetAsync(d_out, 0, (size_t)out_size * sizeof(float), stream);

  cvt_value_kernel<<<2048, 256, 0, stream>>>(value, vbf, (BB * DD) / 4);
  mask_cvt_kernel<0><<<2048, 256, 0, stream>>>(W1, w1m, (HH * DD) / 4);
  mask_cvt_kernel<1><<<2048, 256, 0, stream>>>(W2, w2m, (HH * HH) / 4);
  mask_cvt_kernel<2><<<2048, 256, 0, stream>>>(W3, w3m, (DD * HH) / 4);

  dim3 g12(16, BB / 128);
  gemm_kernel<0, 1, 128><<<g12, 256, 0, stream>>>(vbf, w1m, b1, h1, nullptr, nullptr, BB, HH, DD);
  gemm_kernel<0, 2, 128><<<g12, 256, 0, stream>>>(h1, w2m, b2, h2, nullptr, nullptr, BB, HH, HH);
  dim3 g3(8, BB / 64);
  gemm_kernel<1, 3, 64><<<g3, 256, 0, stream>>>(h2, w3m, b3, nullptr, value, out, BB, DD, HH);
}